// Round 3
// baseline (645.685 us; speedup 1.0000x reference)
//
#include <hip/hip_runtime.h>

#define BB 16
#define CC 384
#define CH 64
#define CF 193
#define HW 16384   // 128*128

#define TWO_PI_OVER_CC (6.283185307179586f / (float)CC)

// ---------------- Kernel 1: global average pool ----------------
// x: [B, C, H, W] fp32; block (c, b) reduces one 64 KB plane.
// Output transposed: y0T[c*16 + b] (batch-fast for coalesced downstream reads).
__global__ __launch_bounds__(256) void pool_kernel(const float4* __restrict__ x,
                                                   float* __restrict__ y0T) {
    const int c = blockIdx.x, b = blockIdx.y;
    const float4* p = x + (size_t)(b * CC + c) * (HW / 4);
    const int t = threadIdx.x;

    float s = 0.f;
#pragma unroll
    for (int r = 0; r < HW / 4 / 256; ++r) {      // 16 iterations
        float4 v = p[t + 256 * r];
        s += v.x + v.y + v.z + v.w;
    }
#pragma unroll
    for (int off = 32; off > 0; off >>= 1) s += __shfl_down(s, off);

    __shared__ float red[4];
    const int wid = t >> 6, lane = t & 63;
    if (lane == 0) red[wid] = s;
    __syncthreads();
    if (t == 0) {
        float tot = red[0] + red[1] + red[2] + red[3];
        y0T[c * BB + b] = tot * (1.0f / (float)HW);
    }
}

// ---------------- Kernel 2: fc1 + relu ----------------
// thread = (j, b): b = t&15 (lane-fast), j = bx*16 + t>>4. Grid 4 x 256.
__global__ __launch_bounds__(256) void fc1_kernel(const float* __restrict__ y0T,
                                                  const float* __restrict__ W1,
                                                  const float* __restrict__ b1,
                                                  float* __restrict__ hT) {
    const int t = threadIdx.x;
    const int b = t & 15;
    const int j = blockIdx.x * 16 + (t >> 4);
    const float* w = W1 + (size_t)j * CC * 9 + 4;   // center taps, stride 9
    float acc = b1[j];
#pragma unroll 4
    for (int c = 0; c < CC; ++c) acc += y0T[c * BB + b] * w[c * 9];
    hT[j * BB + b] = fmaxf(acc, 0.f);
}

// ---------------- Kernel 3: fc2 + sigmoid ----------------
// thread = (c, b). Grid 24 x 256. yT[c*16+b] = sigmoid(...)
__global__ __launch_bounds__(256) void fc2_kernel(const float* __restrict__ hT,
                                                  const float* __restrict__ W2,
                                                  const float* __restrict__ b2,
                                                  float* __restrict__ yT) {
    const int t = threadIdx.x;
    const int b = t & 15;
    const int c = blockIdx.x * 16 + (t >> 4);
    const float* w = W2 + (size_t)c * CH * 9 + 4;
    float acc = b2[c];
#pragma unroll 4
    for (int j = 0; j < CH; ++j) acc += hT[j * BB + b] * w[j * 9];
    yT[c * BB + b] = 1.f / (1.f + expf(-acc));
}

// ---------------- Kernel 4: s1/s2 + rfft + amp/phase recombine ----------------
// thread = (k, b): k = bx*16 + t>>4 (193 bins -> 13 blocks). Grid 13 x 256.
__global__ __launch_bounds__(256) void spec_kernel(const float* __restrict__ yT,
                                                   const float* __restrict__ Ws1,
                                                   const float* __restrict__ bs1,
                                                   const float* __restrict__ Ws2,
                                                   const float* __restrict__ bs2,
                                                   float* __restrict__ rr,
                                                   float* __restrict__ ri) {
    __shared__ float ct[CC], st[CC];
    const int t = threadIdx.x;
    for (int i = t; i < CC; i += 256) {
        float sv, cv; sincosf((float)i * TWO_PI_OVER_CC, &sv, &cv);
        ct[i] = cv; st[i] = sv;
    }
    __syncthreads();

    const int b = t & 15;
    const int k = blockIdx.x * 16 + (t >> 4);      // k <= 207 < 384
    if (k >= CF) return;

    const float* w1 = Ws1 + (size_t)k * CC;
    const float* w2 = Ws2 + (size_t)k * CC;
    float a1 = bs1[k], a2 = bs2[k];
    float re = 0.f, im = 0.f;
    int m = 0;                                     // (k*c) % 384
#pragma unroll 4
    for (int c = 0; c < CC; ++c) {
        float yc = yT[c * BB + b];
        a1 += yc * w1[c];
        a2 += yc * w2[c];
        re += yc * ct[m];
        im -= yc * st[m];
        m += k; if (m >= CC) m -= CC;
    }
    a1 = fmaxf(a1, 0.f);
    a2 = fmaxf(a2, 0.f);
    float amp = sqrtf(re * re + im * im) * a1;
    float pha = atan2f(im, re) * a2;
    float sp, cp; sincosf(pha, &sp, &cp);
    rr[k * BB + b] = amp * cp;
    ri[k * BB + b] = amp * sp;
}

// ---------------- Kernel 5: irfft + final mul ----------------
// thread = (b, c): c = bx*16 + (t&15) lane-fast (coalesced out), b = t>>4.
// Grid 24 x 256.
__global__ __launch_bounds__(256) void irfft_kernel(const float* __restrict__ yT,
                                                    const float* __restrict__ rr,
                                                    const float* __restrict__ ri,
                                                    float* __restrict__ out) {
    __shared__ float ct[CC], st[CC];
    const int t = threadIdx.x;
    for (int i = t; i < CC; i += 256) {
        float sv, cv; sincosf((float)i * TWO_PI_OVER_CC, &sv, &cv);
        ct[i] = cv; st[i] = sv;
    }
    __syncthreads();

    const int c = blockIdx.x * 16 + (t & 15);      // c < 384
    const int b = t >> 4;

    float acc = 0.f;
    int m = 0;                                     // (k*c) % 384
#pragma unroll 4
    for (int k = 1; k < 192; ++k) {
        m += c; if (m >= CC) m -= CC;
        acc += rr[k * BB + b] * ct[m] - ri[k * BB + b] * st[m];
    }
    float nyq = (c & 1) ? -rr[192 * BB + b] : rr[192 * BB + b];
    float xr = (rr[b] + 2.f * acc + nyq) * (1.0f / (float)CC);
    out[b * CC + c] = xr * yT[c * BB + b];
}

extern "C" void kernel_launch(void* const* d_in, const int* in_sizes, int n_in,
                              void* d_out, int out_size, void* d_ws, size_t ws_size,
                              hipStream_t stream) {
    const float4* x  = (const float4*)d_in[0];
    const float* W1  = (const float*)d_in[1];
    const float* b1  = (const float*)d_in[2];
    const float* W2  = (const float*)d_in[3];
    const float* b2  = (const float*)d_in[4];
    const float* Ws1 = (const float*)d_in[5];
    const float* bs1 = (const float*)d_in[6];
    const float* Ws2 = (const float*)d_in[7];
    const float* bs2 = (const float*)d_in[8];
    float* out = (float*)d_out;

    float* ws  = (float*)d_ws;
    float* y0T = ws;                 // 384*16
    float* hT  = y0T + CC * BB;      // 64*16
    float* yT  = hT  + CH * BB;      // 384*16
    float* rr  = yT  + CC * BB;      // 193*16
    float* ri  = rr  + CF * BB;      // 193*16

    pool_kernel <<<dim3(CC, BB), 256, 0, stream>>>(x, y0T);
    fc1_kernel  <<<CH / 16,      256, 0, stream>>>(y0T, W1, b1, hT);
    fc2_kernel  <<<CC / 16,      256, 0, stream>>>(hT, W2, b2, yT);
    spec_kernel <<<(CF + 15)/16, 256, 0, stream>>>(yT, Ws1, bs1, Ws2, bs2, rr, ri);
    irfft_kernel<<<CC / 16,      256, 0, stream>>>(yT, rr, ri, out);
}